// Round 2
// baseline (155.416 us; speedup 1.0000x reference)
//
#include <hip/hip_runtime.h>

#define B_DIM 256
#define I_DIM 128
#define O_DIM 128
#define H_DIM 32
#define F_DIM 7
#define ICHUNK 8
#define NCHUNK (I_DIM / ICHUNK)   // 16

// Pre-kernel: feat[i][b][8] = {x, sin x, sin 2x, sin 4x, cos x, cos 2x, cos 4x, 1}
// 1 MB total, L2-resident; computed ONCE instead of 512x redundantly.
__global__ __launch_bounds__(256, 8)
void feat_kernel(const float* __restrict__ x, float* __restrict__ feat) {
    const int i = blockIdx.x;
    const int b = threadIdx.x;
    float xv = x[(size_t)b * I_DIM + i];
    float s1 = __sinf(xv), c1 = __cosf(xv);
    float s2 = 2.f * s1 * c1, c2 = 1.f - 2.f * s1 * s1;
    float s4 = 2.f * s2 * c2, c4 = 1.f - 2.f * s2 * s2;
    float4* p = reinterpret_cast<float4*>(feat + ((size_t)i * B_DIM + b) * 8);
    p[0] = make_float4(xv, s1, s2, s4);
    p[1] = make_float4(c1, c2, c4, 1.0f);
}

// Main: block = (o, ichunk). hs = tid>>6 (4 h-slices of 8), bg = tid&63,
// thread covers b = bg + 64k (k=0..3) so each LDS weight read feeds 4 FMAs.
// USE_FEAT=false fallback computes trig inline (if ws too small).
template <bool USE_FEAT>
__global__ __launch_bounds__(256, 8)
void fcnkan_main(const float* __restrict__ feat,
                 const float* __restrict__ x,
                 const float* __restrict__ W1,
                 const float* __restrict__ W2,
                 const float* __restrict__ B1,
                 const float* __restrict__ B2,
                 float* __restrict__ out) {
    __shared__ float w1b1[ICHUNK * H_DIM * 8];   // [il][h][8]: w0..w6, B1 -> 8 KiB
    __shared__ float w2s[ICHUNK * H_DIM];        // 1 KiB
    __shared__ float b2s[ICHUNK];
    __shared__ float red[4][B_DIM];              // 4 KiB

    const int tid = threadIdx.x;
    const int o   = blockIdx.x;
    const int ic0 = blockIdx.y * ICHUNK;

    for (int e = tid; e < ICHUNK * H_DIM * F_DIM; e += 256) {
        int il = e / (H_DIM * F_DIM);
        int r  = e - il * (H_DIM * F_DIM);
        int h  = r / F_DIM;
        int f  = r - h * F_DIM;
        w1b1[(il * H_DIM + h) * 8 + f] =
            W1[(size_t)((ic0 + il) * O_DIM + o) * (H_DIM * F_DIM) + r];
    }
    for (int e = tid; e < ICHUNK * H_DIM; e += 256) {
        int il = e >> 5, h = e & 31;
        int io = (ic0 + il) * O_DIM + o;
        w1b1[(il * H_DIM + h) * 8 + 7] = B1[io * H_DIM + h];
        w2s[e]                         = W2[io * H_DIM + h];
    }
    if (tid < ICHUNK) b2s[tid] = B2[(ic0 + tid) * O_DIM + o];
    __syncthreads();

    const int hs = tid >> 6;
    const int bg = tid & 63;

    float acc[4] = {0.f, 0.f, 0.f, 0.f};

    for (int il = 0; il < ICHUNK; ++il) {
        float4 fa[4], fb[4];
        if (USE_FEAT) {
            const float4* fp = reinterpret_cast<const float4*>(
                feat + ((size_t)(ic0 + il) * B_DIM) * 8);
            #pragma unroll
            for (int k = 0; k < 4; ++k) {
                fa[k] = fp[(bg + 64 * k) * 2];
                fb[k] = fp[(bg + 64 * k) * 2 + 1];
            }
        } else {
            #pragma unroll
            for (int k = 0; k < 4; ++k) {
                float xv = x[(size_t)(bg + 64 * k) * I_DIM + ic0 + il];
                float s1 = __sinf(xv), c1 = __cosf(xv);
                float s2 = 2.f * s1 * c1, c2 = 1.f - 2.f * s1 * s1;
                float s4 = 2.f * s2 * c2, c4 = 1.f - 2.f * s2 * s2;
                fa[k] = make_float4(xv, s1, s2, s4);
                fb[k] = make_float4(c1, c2, c4, 1.0f);
            }
        }
        const float4* wrow  = reinterpret_cast<const float4*>(w1b1 + il * H_DIM * 8);
        const float*  w2row = w2s + il * H_DIM + hs * 8;
        #pragma unroll
        for (int h = 0; h < 8; ++h) {
            float4 wa  = wrow[(hs * 8 + h) * 2];
            float4 wb  = wrow[(hs * 8 + h) * 2 + 1];
            float  w2v = w2row[h];
            #pragma unroll
            for (int k = 0; k < 4; ++k) {
                float z = wa.x * fa[k].x;
                z = fmaf(wa.y, fa[k].y, z);
                z = fmaf(wa.z, fa[k].z, z);
                z = fmaf(wa.w, fa[k].w, z);
                z = fmaf(wb.x, fb[k].x, z);
                z = fmaf(wb.y, fb[k].y, z);
                z = fmaf(wb.z, fb[k].z, z);
                z = fmaf(wb.w, fb[k].w, z);          // + B1 via feat[7]==1
                float ev = __expf(-z);
                float sg = __builtin_amdgcn_rcpf(1.f + ev);
                acc[k] = fmaf(z * sg, w2v, acc[k]);
            }
        }
    }

    #pragma unroll
    for (int k = 0; k < 4; ++k) red[hs][bg + 64 * k] = acc[k];
    __syncthreads();

    float b2c = 0.f;
    #pragma unroll
    for (int il = 0; il < ICHUNK; ++il) b2c += b2s[il];

    float total = red[0][tid] + red[1][tid] + red[2][tid] + red[3][tid] + b2c;
    atomicAdd(&out[(size_t)tid * O_DIM + o], total);
}

extern "C" void kernel_launch(void* const* d_in, const int* in_sizes, int n_in,
                              void* d_out, int out_size, void* d_ws, size_t ws_size,
                              hipStream_t stream) {
    const float* x  = (const float*)d_in[0];
    const float* W1 = (const float*)d_in[1];
    const float* W2 = (const float*)d_in[2];
    const float* B1 = (const float*)d_in[3];
    const float* B2 = (const float*)d_in[4];
    float* out  = (float*)d_out;
    float* feat = (float*)d_ws;

    const size_t feat_bytes = (size_t)I_DIM * B_DIM * 8 * sizeof(float); // 1 MiB
    const bool use_feat = (ws_size >= feat_bytes);  // launch-invariant -> graph-safe

    hipMemsetAsync(out, 0, (size_t)out_size * sizeof(float), stream);
    dim3 grid(O_DIM, NCHUNK);
    if (use_feat) {
        feat_kernel<<<I_DIM, B_DIM, 0, stream>>>(x, feat);
        fcnkan_main<true><<<grid, 256, 0, stream>>>(feat, x, W1, W2, B1, B2, out);
    } else {
        fcnkan_main<false><<<grid, 256, 0, stream>>>(feat, x, W1, W2, B1, B2, out);
    }
}

// Round 3
// 131.021 us; speedup vs baseline: 1.1862x; 1.1862x over previous
//
#include <hip/hip_runtime.h>

#define B_DIM 256
#define I_DIM 128
#define O_DIM 128
#define H_DIM 32
#define F_DIM 7
#define ICHUNK 8
#define NCHUNK (I_DIM / ICHUNK)   // 16

// Pre-kernel: feat[i][b][8] = {x, sin x, sin 2x, sin 4x, cos x, cos 2x, cos 4x, 1}
// 1 MB total, L2-resident; computed ONCE instead of 512x redundantly.
__global__ void feat_kernel(const float* __restrict__ x, float* __restrict__ feat) {
    const int i = blockIdx.x;
    const int b = threadIdx.x;
    float xv = x[(size_t)b * I_DIM + i];
    float s1 = __sinf(xv), c1 = __cosf(xv);
    float s2 = 2.f * s1 * c1, c2 = 1.f - 2.f * s1 * s1;
    float s4 = 2.f * s2 * c2, c4 = 1.f - 2.f * s2 * s2;
    float4* p = reinterpret_cast<float4*>(feat + ((size_t)i * B_DIM + b) * 8);
    p[0] = make_float4(xv, s1, s2, s4);
    p[1] = make_float4(c1, c2, c4, 1.0f);
}

// Main: block = (o, ichunk). hs = tid>>6 (4 h-slices of 8), bg = tid&63,
// thread covers b = bg + 64k (k=0..3) so each LDS weight read feeds 4 FMAs.
// launch_bounds(256,4): VGPR cap 128 — (256,8) capped at 32 and SPILLED
// (R2: 137 MB scratch writes). Do not tighten this again.
template <bool USE_FEAT>
__global__ __launch_bounds__(256, 4)
void fcnkan_main(const float* __restrict__ feat,
                 const float* __restrict__ x,
                 const float* __restrict__ W1,
                 const float* __restrict__ W2,
                 const float* __restrict__ B1,
                 const float* __restrict__ B2,
                 float* __restrict__ out) {
    __shared__ float w1b1[ICHUNK * H_DIM * 8];   // [il][h][8]: w0..w6, B1 -> 8 KiB
    __shared__ float w2s[ICHUNK * H_DIM];        // 1 KiB
    __shared__ float b2s[ICHUNK];
    __shared__ float red[4][B_DIM];              // 4 KiB

    const int tid = threadIdx.x;
    const int o   = blockIdx.x;
    const int ic0 = blockIdx.y * ICHUNK;

    for (int e = tid; e < ICHUNK * H_DIM * F_DIM; e += 256) {
        int il = e / (H_DIM * F_DIM);
        int r  = e - il * (H_DIM * F_DIM);
        int h  = r / F_DIM;
        int f  = r - h * F_DIM;
        w1b1[(il * H_DIM + h) * 8 + f] =
            W1[(size_t)((ic0 + il) * O_DIM + o) * (H_DIM * F_DIM) + r];
    }
    for (int e = tid; e < ICHUNK * H_DIM; e += 256) {
        int il = e >> 5, h = e & 31;
        int io = (ic0 + il) * O_DIM + o;
        w1b1[(il * H_DIM + h) * 8 + 7] = B1[io * H_DIM + h];
        w2s[e]                         = W2[io * H_DIM + h];
    }
    if (tid < ICHUNK) b2s[tid] = B2[(ic0 + tid) * O_DIM + o];
    __syncthreads();

    const int hs = tid >> 6;
    const int bg = tid & 63;

    float acc[4] = {0.f, 0.f, 0.f, 0.f};

    for (int il = 0; il < ICHUNK; ++il) {
        float4 fa[4], fb[4];
        if (USE_FEAT) {
            const float4* fp = reinterpret_cast<const float4*>(
                feat + ((size_t)(ic0 + il) * B_DIM) * 8);
            #pragma unroll
            for (int k = 0; k < 4; ++k) {
                fa[k] = fp[(bg + 64 * k) * 2];
                fb[k] = fp[(bg + 64 * k) * 2 + 1];
            }
        } else {
            #pragma unroll
            for (int k = 0; k < 4; ++k) {
                float xv = x[(size_t)(bg + 64 * k) * I_DIM + ic0 + il];
                float s1 = __sinf(xv), c1 = __cosf(xv);
                float s2 = 2.f * s1 * c1, c2 = 1.f - 2.f * s1 * s1;
                float s4 = 2.f * s2 * c2, c4 = 1.f - 2.f * s2 * s2;
                fa[k] = make_float4(xv, s1, s2, s4);
                fb[k] = make_float4(c1, c2, c4, 1.0f);
            }
        }
        const float4* wrow  = reinterpret_cast<const float4*>(w1b1 + il * H_DIM * 8);
        const float*  w2row = w2s + il * H_DIM + hs * 8;
        #pragma unroll
        for (int h = 0; h < 8; ++h) {
            float4 wa  = wrow[(hs * 8 + h) * 2];
            float4 wb  = wrow[(hs * 8 + h) * 2 + 1];
            float  w2v = w2row[h];
            #pragma unroll
            for (int k = 0; k < 4; ++k) {
                float z = wa.x * fa[k].x;
                z = fmaf(wa.y, fa[k].y, z);
                z = fmaf(wa.z, fa[k].z, z);
                z = fmaf(wa.w, fa[k].w, z);
                z = fmaf(wb.x, fb[k].x, z);
                z = fmaf(wb.y, fb[k].y, z);
                z = fmaf(wb.z, fb[k].z, z);
                z = fmaf(wb.w, fb[k].w, z);          // + B1 via feat[7]==1
                float ev = __expf(-z);
                float sg = __builtin_amdgcn_rcpf(1.f + ev);
                acc[k] = fmaf(z * sg, w2v, acc[k]);
            }
        }
    }

    #pragma unroll
    for (int k = 0; k < 4; ++k) red[hs][bg + 64 * k] = acc[k];
    __syncthreads();

    float b2c = 0.f;
    #pragma unroll
    for (int il = 0; il < ICHUNK; ++il) b2c += b2s[il];

    float total = red[0][tid] + red[1][tid] + red[2][tid] + red[3][tid] + b2c;
    atomicAdd(&out[(size_t)tid * O_DIM + o], total);
}

extern "C" void kernel_launch(void* const* d_in, const int* in_sizes, int n_in,
                              void* d_out, int out_size, void* d_ws, size_t ws_size,
                              hipStream_t stream) {
    const float* x  = (const float*)d_in[0];
    const float* W1 = (const float*)d_in[1];
    const float* W2 = (const float*)d_in[2];
    const float* B1 = (const float*)d_in[3];
    const float* B2 = (const float*)d_in[4];
    float* out  = (float*)d_out;
    float* feat = (float*)d_ws;

    const size_t feat_bytes = (size_t)I_DIM * B_DIM * 8 * sizeof(float); // 1 MiB
    const bool use_feat = (ws_size >= feat_bytes);  // launch-invariant -> graph-safe

    hipMemsetAsync(out, 0, (size_t)out_size * sizeof(float), stream);
    dim3 grid(O_DIM, NCHUNK);
    if (use_feat) {
        feat_kernel<<<I_DIM, B_DIM, 0, stream>>>(x, feat);
        fcnkan_main<true><<<grid, 256, 0, stream>>>(feat, x, W1, W2, B1, B2, out);
    } else {
        fcnkan_main<false><<<grid, 256, 0, stream>>>(feat, x, W1, W2, B1, B2, out);
    }
}